// Round 1
// baseline (441.168 us; speedup 1.0000x reference)
//
#include <hip/hip_runtime.h>
#include <math.h>

#define D 128
#define NPARAMS 16
#define H 256
#define XCOLS (D + NPARAMS)   // 144
#define BATCH 4096
#define NTOT (BATCH * D)      // 524288
#define NS 8                  // samples per MLP block

#define TWO_PI_F 6.28318530717958647692f
#define PI_F     3.14159265358979323846f

// ---------------- MLP: params(16) -> 256 -> 256 -> 256 -> coef(256) ----------
// Thread j computes output unit j for NS samples. Activations in LDS [k][s]
// (broadcast reads across lanes -> conflict-free).

#define LAYER256(WP, BP, SRC) {                                        \
    float bb = (BP)[j];                                                \
    _Pragma("unroll") for (int s = 0; s < NS; ++s) acc[s] = bb;        \
    const float4* w4 = reinterpret_cast<const float4*>((WP) + j * H);  \
    for (int k4 = 0; k4 < H / 4; ++k4) {                               \
        float4 wv = w4[k4];                                            \
        int k = k4 * 4;                                                \
        _Pragma("unroll") for (int s = 0; s < NS; ++s)                 \
            acc[s] = fmaf(wv.x, SRC[k][s], acc[s]);                    \
        _Pragma("unroll") for (int s = 0; s < NS; ++s)                 \
            acc[s] = fmaf(wv.y, SRC[k + 1][s], acc[s]);                \
        _Pragma("unroll") for (int s = 0; s < NS; ++s)                 \
            acc[s] = fmaf(wv.z, SRC[k + 2][s], acc[s]);                \
        _Pragma("unroll") for (int s = 0; s < NS; ++s)                 \
            acc[s] = fmaf(wv.w, SRC[k + 3][s], acc[s]);                \
    }                                                                  \
}

__global__ __launch_bounds__(256) void mlp_kernel(
    const float* __restrict__ x,
    const float* __restrict__ w_in, const float* __restrict__ b_in,
    const float* __restrict__ w0,   const float* __restrict__ b0,
    const float* __restrict__ w1,   const float* __restrict__ b1,
    const float* __restrict__ w_out,const float* __restrict__ b_out,
    float* __restrict__ w2buf, float* __restrict__ cbuf)
{
    __shared__ float hA[H][NS];
    __shared__ float hB[H][NS];
    const int j = threadIdx.x;
    const int bbase = blockIdx.x * NS;

    // stage params into hA[k][s], k < 16
    if (j < NPARAMS * NS) {
        int k = j / NS, s = j % NS;
        hA[k][s] = x[(bbase + s) * XCOLS + D + k];
    }
    __syncthreads();

    float acc[NS];

    // layer in: 16 -> 256, relu   (hA -> hB)
    {
        float bb = b_in[j];
        #pragma unroll
        for (int s = 0; s < NS; ++s) acc[s] = bb;
        #pragma unroll
        for (int k = 0; k < NPARAMS; ++k) {
            float wv = w_in[j * NPARAMS + k];
            #pragma unroll
            for (int s = 0; s < NS; ++s) acc[s] = fmaf(wv, hA[k][s], acc[s]);
        }
        #pragma unroll
        for (int s = 0; s < NS; ++s) hB[j][s] = fmaxf(acc[s], 0.f);
    }
    __syncthreads();

    // layer 0: 256 -> 256, relu   (hB -> hA)
    LAYER256(w0, b0, hB);
    #pragma unroll
    for (int s = 0; s < NS; ++s) hA[j][s] = fmaxf(acc[s], 0.f);
    __syncthreads();

    // layer 1: 256 -> 256, relu   (hA -> hB)
    LAYER256(w1, b1, hA);
    #pragma unroll
    for (int s = 0; s < NS; ++s) hB[j][s] = fmaxf(acc[s], 0.f);
    __syncthreads();

    // out layer: 256 -> 256 coef  (reads hB), epilogue to global
    LAYER256(w_out, b_out, hB);
    #pragma unroll
    for (int s = 0; s < NS; ++s) {
        float coef = acc[s];
        int b = bbase + s;
        if (j < D) {
            float om = fmaf(coef, 1.5f, 0.5f);     // omega0 in phys units
            w2buf[b * D + j] = om * om;            // omega0^2
        } else {
            cbuf[b * D + (j - D)] = coef;          // coupling (C range [0,1] affine = identity)
        }
    }
}

// ---------------- ODE: per-sample 128-oscillator chain, RK4 ------------------
// One wave (64 lanes) per sample; lane l owns oscillators l and l+64.
// Neighbor exchange purely via shuffles; no LDS, no barriers.

__global__ __launch_bounds__(256) void ode_kernel(
    const float* __restrict__ x,
    const float* __restrict__ w2buf,
    const float* __restrict__ cbuf,
    float* __restrict__ out,
    int nstep, float dt)
{
    const int lane = threadIdx.x & 63;
    const int wid  = threadIdx.x >> 6;
    const int b    = blockIdx.x * 4 + wid;
    const int i0   = b * D + lane;
    const int i1   = i0 + 64;

    float th0 = fmaf(x[b * XCOLS + lane],      TWO_PI_F, -PI_F);
    float th1 = fmaf(x[b * XCOLS + 64 + lane], TWO_PI_F, -PI_F);
    float v0 = 0.f, v1 = 0.f;

    const float w20 = w2buf[i0];
    const float w21 = w2buf[i1];
    const float c0  = cbuf[i0];
    const float c1  = cbuf[i1];
    const float cl0 = cbuf[(i0 + NTOT - 1) % NTOT];  // global roll across flattened array
    const float cl1 = cbuf[i1 - 1];

    const int lm = (lane + 63) & 63;
    const int lp = (lane + 1) & 63;

    auto deriv = [&](float t0, float t1, float& a0, float& a1) {
        float r0 = __shfl(t0, lm);
        float r1 = __shfl(t1, lm);
        float s0 = __shfl(t0, lp);
        float s1 = __shfl(t1, lp);
        float L0 = (lane == 0)  ? r1 : r0;  // left neighbor of osc l
        float L1 = (lane == 0)  ? r0 : r1;  // left neighbor of osc l+64
        float R0 = (lane == 63) ? s1 : s0;  // right neighbor of osc l
        float R1 = (lane == 63) ? s0 : s1;  // right neighbor of osc l+64
        a0 = fmaf(-__sinf(t0), w20, fmaf(cl0, L0 - t0, c0 * (R0 - t0)));
        a1 = fmaf(-__sinf(t1), w21, fmaf(cl1, L1 - t1, c1 * (R1 - t1)));
    };

    const float hdt   = 0.5f * dt;
    const float sixth = dt * (1.0f / 6.0f);

    for (int it = 0; it < nstep; ++it) {
        float a10, a11; deriv(th0, th1, a10, a11);
        float k1t0 = v0, k1t1 = v1;

        float t20 = fmaf(hdt, k1t0, th0), t21 = fmaf(hdt, k1t1, th1);
        float k2t0 = fmaf(hdt, a10, v0),  k2t1 = fmaf(hdt, a11, v1);
        float a20, a21; deriv(t20, t21, a20, a21);

        float t30 = fmaf(hdt, k2t0, th0), t31 = fmaf(hdt, k2t1, th1);
        float k3t0 = fmaf(hdt, a20, v0),  k3t1 = fmaf(hdt, a21, v1);
        float a30, a31; deriv(t30, t31, a30, a31);

        float t40 = fmaf(dt, k3t0, th0),  t41 = fmaf(dt, k3t1, th1);
        float k4t0 = fmaf(dt, a30, v0),   k4t1 = fmaf(dt, a31, v1);
        float a40, a41; deriv(t40, t41, a40, a41);

        th0 += sixth * (k1t0 + 2.f * (k2t0 + k3t0) + k4t0);
        th1 += sixth * (k1t1 + 2.f * (k2t1 + k3t1) + k4t1);
        v0  += sixth * (a10  + 2.f * (a20  + a30 ) + a40);
        v1  += sixth * (a11  + 2.f * (a21  + a31 ) + a41);
    }

    out[i0] = th0 * 0.4f;   // (theta - 0)/2.5
    out[i1] = th1 * 0.4f;
}

extern "C" void kernel_launch(void* const* d_in, const int* in_sizes, int n_in,
                              void* d_out, int out_size, void* d_ws, size_t ws_size,
                              hipStream_t stream) {
    const float* x     = (const float*)d_in[0];
    const float* w_in  = (const float*)d_in[1];
    const float* b_in  = (const float*)d_in[2];
    const float* w0    = (const float*)d_in[3];
    const float* b0    = (const float*)d_in[4];
    const float* w1    = (const float*)d_in[5];
    const float* b1    = (const float*)d_in[6];
    const float* w_out = (const float*)d_in[7];
    const float* b_out = (const float*)d_in[8];

    float* w2buf = (float*)d_ws;          // omega0^2, NTOT floats
    float* cbuf  = w2buf + NTOT;          // coupling, NTOT floats
    float* out   = (float*)d_out;

    mlp_kernel<<<BATCH / NS, 256, 0, stream>>>(x, w_in, b_in, w0, b0, w1, b1,
                                               w_out, b_out, w2buf, cbuf);

    const int nstep = 512;
    const float dtf = (float)((59.0 / 30.0) / nstep);
    ode_kernel<<<BATCH / 4, 256, 0, stream>>>(x, w2buf, cbuf, out, nstep, dtf);
}

// Round 2
// 191.827 us; speedup vs baseline: 2.2998x; 2.2998x over previous
//
#include <hip/hip_runtime.h>
#include <math.h>

#define D 128
#define NPARAMS 16
#define H 256
#define XCOLS (D + NPARAMS)   // 144
#define BATCH 4096
#define NTOT (BATCH * D)      // 524288
#define NS 8                  // samples per MLP block

#define TWO_PI_F 6.28318530717958647692f
#define PI_F     3.14159265358979323846f

// ---------------- MLP: params(16) -> 256 -> 256 -> 256 -> coef(256) ----------

#define LAYER256(WP, BP, SRC) {                                        \
    float bb = (BP)[j];                                                \
    _Pragma("unroll") for (int s = 0; s < NS; ++s) acc[s] = bb;        \
    const float4* w4 = reinterpret_cast<const float4*>((WP) + j * H);  \
    for (int k4 = 0; k4 < H / 4; ++k4) {                               \
        float4 wv = w4[k4];                                            \
        int k = k4 * 4;                                                \
        _Pragma("unroll") for (int s = 0; s < NS; ++s)                 \
            acc[s] = fmaf(wv.x, SRC[k][s], acc[s]);                    \
        _Pragma("unroll") for (int s = 0; s < NS; ++s)                 \
            acc[s] = fmaf(wv.y, SRC[k + 1][s], acc[s]);                \
        _Pragma("unroll") for (int s = 0; s < NS; ++s)                 \
            acc[s] = fmaf(wv.z, SRC[k + 2][s], acc[s]);                \
        _Pragma("unroll") for (int s = 0; s < NS; ++s)                 \
            acc[s] = fmaf(wv.w, SRC[k + 3][s], acc[s]);                \
    }                                                                  \
}

__global__ __launch_bounds__(256) void mlp_kernel(
    const float* __restrict__ x,
    const float* __restrict__ w_in, const float* __restrict__ b_in,
    const float* __restrict__ w0,   const float* __restrict__ b0,
    const float* __restrict__ w1,   const float* __restrict__ b1,
    const float* __restrict__ w_out,const float* __restrict__ b_out,
    float* __restrict__ w2buf, float* __restrict__ cbuf)
{
    __shared__ float hA[H][NS];
    __shared__ float hB[H][NS];
    const int j = threadIdx.x;
    const int bbase = blockIdx.x * NS;

    if (j < NPARAMS * NS) {
        int k = j / NS, s = j % NS;
        hA[k][s] = x[(bbase + s) * XCOLS + D + k];
    }
    __syncthreads();

    float acc[NS];

    // layer in: 16 -> 256, relu   (hA -> hB)
    {
        float bb = b_in[j];
        #pragma unroll
        for (int s = 0; s < NS; ++s) acc[s] = bb;
        #pragma unroll
        for (int k = 0; k < NPARAMS; ++k) {
            float wv = w_in[j * NPARAMS + k];
            #pragma unroll
            for (int s = 0; s < NS; ++s) acc[s] = fmaf(wv, hA[k][s], acc[s]);
        }
        #pragma unroll
        for (int s = 0; s < NS; ++s) hB[j][s] = fmaxf(acc[s], 0.f);
    }
    __syncthreads();

    LAYER256(w0, b0, hB);
    #pragma unroll
    for (int s = 0; s < NS; ++s) hA[j][s] = fmaxf(acc[s], 0.f);
    __syncthreads();

    LAYER256(w1, b1, hA);
    #pragma unroll
    for (int s = 0; s < NS; ++s) hB[j][s] = fmaxf(acc[s], 0.f);
    __syncthreads();

    LAYER256(w_out, b_out, hB);
    #pragma unroll
    for (int s = 0; s < NS; ++s) {
        float coef = acc[s];
        int b = bbase + s;
        if (j < D) {
            float om = fmaf(coef, 1.5f, 0.5f);     // omega0
            w2buf[b * D + j] = om * om;            // omega0^2
        } else {
            cbuf[b * D + (j - D)] = coef;          // coupling (identity affine)
        }
    }
}

// ---------------- ODE: per-sample 128-oscillator chain, RK4 ------------------
// One wave per sample; lane l owns oscillators 2l and 2l+1 (contiguous pair).
// Right neighbor of 2l and left neighbor of 2l+1 are in-register; the two
// cross-lane exchanges wrap circularly with (l +/- 1) & 63 -> no edge selects.

__global__ __launch_bounds__(256) void ode_kernel(
    const float* __restrict__ x,
    const float* __restrict__ w2buf,
    const float* __restrict__ cbuf,
    float* __restrict__ out,
    int nstep, float dt)
{
    const int lane = threadIdx.x & 63;
    const int wid  = threadIdx.x >> 6;
    const int b    = blockIdx.x * 4 + wid;
    const int i0   = b * D + 2 * lane;   // even: float2-aligned

    float2 xi = *reinterpret_cast<const float2*>(&x[b * XCOLS + 2 * lane]);
    float th0 = fmaf(xi.x, TWO_PI_F, -PI_F);
    float th1 = fmaf(xi.y, TWO_PI_F, -PI_F);
    float v0 = 0.f, v1 = 0.f;

    float2 w2p = *reinterpret_cast<const float2*>(&w2buf[i0]);
    float2 cp  = *reinterpret_cast<const float2*>(&cbuf[i0]);
    const float nw20 = -w2p.x, nw21 = -w2p.y;
    const float c0 = cp.x, c1 = cp.y;
    const float cl0 = cbuf[(i0 + NTOT - 1) % NTOT];  // flat-roll left coupling of osc 2l

    const int lm = (lane + 63) & 63;
    const int lp = (lane + 1) & 63;

    auto deriv = [&](float t0, float t1, float& a0, float& a1) {
        float L0 = __shfl(t1, lm);   // osc 2l-1 (wraps to 127 at lane 0)
        float R1 = __shfl(t0, lp);   // osc 2l+2 (wraps to 0 at lane 63)
        float s0 = __sinf(t0);       // issued while shuffles in flight
        float s1 = __sinf(t1);
        a0 = fmaf(s0, nw20, fmaf(cl0, L0 - t0, c0 * (t1 - t0)));
        a1 = fmaf(s1, nw21, fmaf(c0, t0 - t1, c1 * (R1 - t1)));
    };

    const float hdt   = 0.5f * dt;
    const float sixth = dt * (1.0f / 6.0f);

    for (int it = 0; it < nstep; ++it) {
        float a10, a11; deriv(th0, th1, a10, a11);
        float k1t0 = v0, k1t1 = v1;

        float t20 = fmaf(hdt, k1t0, th0), t21 = fmaf(hdt, k1t1, th1);
        float k2t0 = fmaf(hdt, a10, v0),  k2t1 = fmaf(hdt, a11, v1);
        float a20, a21; deriv(t20, t21, a20, a21);

        float t30 = fmaf(hdt, k2t0, th0), t31 = fmaf(hdt, k2t1, th1);
        float k3t0 = fmaf(hdt, a20, v0),  k3t1 = fmaf(hdt, a21, v1);
        float a30, a31; deriv(t30, t31, a30, a31);

        float t40 = fmaf(dt, k3t0, th0),  t41 = fmaf(dt, k3t1, th1);
        float k4t0 = fmaf(dt, a30, v0),   k4t1 = fmaf(dt, a31, v1);
        float a40, a41; deriv(t40, t41, a40, a41);

        th0 += sixth * (k1t0 + 2.f * (k2t0 + k3t0) + k4t0);
        th1 += sixth * (k1t1 + 2.f * (k2t1 + k3t1) + k4t1);
        v0  += sixth * (a10  + 2.f * (a20  + a30 ) + a40);
        v1  += sixth * (a11  + 2.f * (a21  + a31 ) + a41);
    }

    float2 o = make_float2(th0 * 0.4f, th1 * 0.4f);  // (theta - 0)/2.5
    *reinterpret_cast<float2*>(&out[i0]) = o;
}

extern "C" void kernel_launch(void* const* d_in, const int* in_sizes, int n_in,
                              void* d_out, int out_size, void* d_ws, size_t ws_size,
                              hipStream_t stream) {
    const float* x     = (const float*)d_in[0];
    const float* w_in  = (const float*)d_in[1];
    const float* b_in  = (const float*)d_in[2];
    const float* w0    = (const float*)d_in[3];
    const float* b0    = (const float*)d_in[4];
    const float* w1    = (const float*)d_in[5];
    const float* b1    = (const float*)d_in[6];
    const float* w_out = (const float*)d_in[7];
    const float* b_out = (const float*)d_in[8];

    float* w2buf = (float*)d_ws;          // omega0^2, NTOT floats
    float* cbuf  = w2buf + NTOT;          // coupling, NTOT floats
    float* out   = (float*)d_out;

    mlp_kernel<<<BATCH / NS, 256, 0, stream>>>(x, w_in, b_in, w0, b0, w1, b1,
                                               w_out, b_out, w2buf, cbuf);

    const int nstep = 256;
    const float dtf = (float)((59.0 / 30.0) / nstep);
    ode_kernel<<<BATCH / 4, 256, 0, stream>>>(x, w2buf, cbuf, out, nstep, dtf);
}

// Round 3
// 117.419 us; speedup vs baseline: 3.7572x; 1.6337x over previous
//
#include <hip/hip_runtime.h>
#include <math.h>

#define D 128
#define NPARAMS 16
#define H 256
#define XCOLS (D + NPARAMS)   // 144
#define BATCH 4096
#define NTOT (BATCH * D)      // 524288
#define NS 16                 // samples per MLP block

#define TWO_PI_F 6.28318530717958647692f
#define PI_F     3.14159265358979323846f

// ---------------- MLP: params(16) -> 256 -> 256 -> 256 -> coef(256) ----------

#define LAYER256(WP, BP, SRC) {                                        \
    float bb = (BP)[j];                                                \
    _Pragma("unroll") for (int s = 0; s < NS; ++s) acc[s] = bb;        \
    const float4* w4 = reinterpret_cast<const float4*>((WP) + j * H);  \
    for (int k4 = 0; k4 < H / 4; ++k4) {                               \
        float4 wv = w4[k4];                                            \
        int k = k4 * 4;                                                \
        _Pragma("unroll") for (int s = 0; s < NS; ++s)                 \
            acc[s] = fmaf(wv.x, SRC[k][s], acc[s]);                    \
        _Pragma("unroll") for (int s = 0; s < NS; ++s)                 \
            acc[s] = fmaf(wv.y, SRC[k + 1][s], acc[s]);                \
        _Pragma("unroll") for (int s = 0; s < NS; ++s)                 \
            acc[s] = fmaf(wv.z, SRC[k + 2][s], acc[s]);                \
        _Pragma("unroll") for (int s = 0; s < NS; ++s)                 \
            acc[s] = fmaf(wv.w, SRC[k + 3][s], acc[s]);                \
    }                                                                  \
}

__global__ __launch_bounds__(256) void mlp_kernel(
    const float* __restrict__ x,
    const float* __restrict__ w_in, const float* __restrict__ b_in,
    const float* __restrict__ w0,   const float* __restrict__ b0,
    const float* __restrict__ w1,   const float* __restrict__ b1,
    const float* __restrict__ w_out,const float* __restrict__ b_out,
    float* __restrict__ w2buf, float* __restrict__ cbuf)
{
    __shared__ float hA[H][NS];
    __shared__ float hB[H][NS];
    const int j = threadIdx.x;
    const int bbase = blockIdx.x * NS;

    // stage params: 256 threads cover k(16) x s(16) exactly
    {
        int k = j / NS, s = j % NS;
        hA[k][s] = x[(bbase + s) * XCOLS + D + k];
    }
    __syncthreads();

    float acc[NS];

    // layer in: 16 -> 256, relu   (hA -> hB)
    {
        float bb = b_in[j];
        #pragma unroll
        for (int s = 0; s < NS; ++s) acc[s] = bb;
        #pragma unroll
        for (int k = 0; k < NPARAMS; ++k) {
            float wv = w_in[j * NPARAMS + k];
            #pragma unroll
            for (int s = 0; s < NS; ++s) acc[s] = fmaf(wv, hA[k][s], acc[s]);
        }
        #pragma unroll
        for (int s = 0; s < NS; ++s) hB[j][s] = fmaxf(acc[s], 0.f);
    }
    __syncthreads();

    LAYER256(w0, b0, hB);
    #pragma unroll
    for (int s = 0; s < NS; ++s) hA[j][s] = fmaxf(acc[s], 0.f);
    __syncthreads();

    LAYER256(w1, b1, hA);
    #pragma unroll
    for (int s = 0; s < NS; ++s) hB[j][s] = fmaxf(acc[s], 0.f);
    __syncthreads();

    LAYER256(w_out, b_out, hB);
    #pragma unroll
    for (int s = 0; s < NS; ++s) {
        float coef = acc[s];
        int b = bbase + s;
        if (j < D) {
            float om = fmaf(coef, 1.5f, 0.5f);     // omega0
            w2buf[b * D + j] = om * om;            // omega0^2
        } else {
            cbuf[b * D + (j - D)] = coef;          // coupling (identity affine)
        }
    }
}

// ---------------- ODE: per-sample 128-oscillator chain, RK4 ------------------
// One wave per sample; lane l owns oscillators 2l, 2l+1. Cross-lane neighbor
// exchange via DPP wave rotates (full-rate VALU, no LDS pipe, no DS latency).

__device__ __forceinline__ float rot_from_lower(float v) {  // lane n <- lane (n-1)&63
    return __int_as_float(__builtin_amdgcn_mov_dpp(__float_as_int(v), 0x13C, 0xF, 0xF, false)); // wave_ror:1
}
__device__ __forceinline__ float rot_from_upper(float v) {  // lane n <- lane (n+1)&63
    return __int_as_float(__builtin_amdgcn_mov_dpp(__float_as_int(v), 0x134, 0xF, 0xF, false)); // wave_rol:1
}

__global__ __launch_bounds__(256) void ode_kernel(
    const float* __restrict__ x,
    const float* __restrict__ w2buf,
    const float* __restrict__ cbuf,
    float* __restrict__ out,
    int nstep, float dt)
{
    const int lane = threadIdx.x & 63;
    const int wid  = threadIdx.x >> 6;
    const int b    = blockIdx.x * 4 + wid;
    const int i0   = b * D + 2 * lane;   // even: float2-aligned

    float2 xi = *reinterpret_cast<const float2*>(&x[b * XCOLS + 2 * lane]);
    float th0 = fmaf(xi.x, TWO_PI_F, -PI_F);
    float th1 = fmaf(xi.y, TWO_PI_F, -PI_F);
    float v0 = 0.f, v1 = 0.f;

    float2 w2p = *reinterpret_cast<const float2*>(&w2buf[i0]);
    float2 cp  = *reinterpret_cast<const float2*>(&cbuf[i0]);
    const float nw20 = -w2p.x, nw21 = -w2p.y;
    const float c0 = cp.x, c1 = cp.y;
    const float cl0 = cbuf[(i0 + NTOT - 1) % NTOT];  // flat-roll left coupling of osc 2l

    auto deriv = [&](float t0, float t1, float& a0, float& a1) {
        float L0 = rot_from_lower(t1);   // theta of osc 2l-1 (wraps 0 -> 127)
        float R1 = rot_from_upper(t0);   // theta of osc 2l+2 (wraps 63 -> 0)
        float s0 = __sinf(t0);
        float s1 = __sinf(t1);
        a0 = fmaf(s0, nw20, fmaf(cl0, L0 - t0, c0 * (t1 - t0)));
        a1 = fmaf(s1, nw21, fmaf(c0, t0 - t1, c1 * (R1 - t1)));
    };

    const float hdt   = 0.5f * dt;
    const float sixth = dt * (1.0f / 6.0f);

    for (int it = 0; it < nstep; ++it) {
        float a10, a11; deriv(th0, th1, a10, a11);
        float k1t0 = v0, k1t1 = v1;

        float t20 = fmaf(hdt, k1t0, th0), t21 = fmaf(hdt, k1t1, th1);
        float k2t0 = fmaf(hdt, a10, v0),  k2t1 = fmaf(hdt, a11, v1);
        float a20, a21; deriv(t20, t21, a20, a21);

        float t30 = fmaf(hdt, k2t0, th0), t31 = fmaf(hdt, k2t1, th1);
        float k3t0 = fmaf(hdt, a20, v0),  k3t1 = fmaf(hdt, a21, v1);
        float a30, a31; deriv(t30, t31, a30, a31);

        float t40 = fmaf(dt, k3t0, th0),  t41 = fmaf(dt, k3t1, th1);
        float k4t0 = fmaf(dt, a30, v0),   k4t1 = fmaf(dt, a31, v1);
        float a40, a41; deriv(t40, t41, a40, a41);

        th0 += sixth * (k1t0 + 2.f * (k2t0 + k3t0) + k4t0);
        th1 += sixth * (k1t1 + 2.f * (k2t1 + k3t1) + k4t1);
        v0  += sixth * (a10  + 2.f * (a20  + a30 ) + a40);
        v1  += sixth * (a11  + 2.f * (a21  + a31 ) + a41);
    }

    float2 o = make_float2(th0 * 0.4f, th1 * 0.4f);  // (theta - 0)/2.5
    *reinterpret_cast<float2*>(&out[i0]) = o;
}

extern "C" void kernel_launch(void* const* d_in, const int* in_sizes, int n_in,
                              void* d_out, int out_size, void* d_ws, size_t ws_size,
                              hipStream_t stream) {
    const float* x     = (const float*)d_in[0];
    const float* w_in  = (const float*)d_in[1];
    const float* b_in  = (const float*)d_in[2];
    const float* w0    = (const float*)d_in[3];
    const float* b0    = (const float*)d_in[4];
    const float* w1    = (const float*)d_in[5];
    const float* b1    = (const float*)d_in[6];
    const float* w_out = (const float*)d_in[7];
    const float* b_out = (const float*)d_in[8];

    float* w2buf = (float*)d_ws;          // omega0^2, NTOT floats
    float* cbuf  = w2buf + NTOT;          // coupling, NTOT floats
    float* out   = (float*)d_out;

    mlp_kernel<<<BATCH / NS, 256, 0, stream>>>(x, w_in, b_in, w0, b0, w1, b1,
                                               w_out, b_out, w2buf, cbuf);

    const int nstep = 128;
    const float dtf = (float)((59.0 / 30.0) / nstep);
    ode_kernel<<<BATCH / 4, 256, 0, stream>>>(x, w2buf, cbuf, out, nstep, dtf);
}

// Round 4
// 87.749 us; speedup vs baseline: 5.0276x; 1.3381x over previous
//
#include <hip/hip_runtime.h>
#include <math.h>

#define D 128
#define NPARAMS 16
#define H 256
#define XCOLS (D + NPARAMS)   // 144
#define BATCH 4096
#define NTOT (BATCH * D)      // 524288
#define NS 8                  // samples per MLP block

#define INV_2PI_F 0.15915494309189535f
#define OUT_SCALE 2.5132741228718345f   // 2*pi / 2.5

// ---------------- MLP: params(16) -> 256 -> 256 -> 256 -> coef(256) ----------

#define LAYER256(WP, BP, SRC) {                                        \
    float bb = (BP)[j];                                                \
    _Pragma("unroll") for (int s = 0; s < NS; ++s) acc[s] = bb;        \
    const float4* w4 = reinterpret_cast<const float4*>((WP) + j * H);  \
    for (int k4 = 0; k4 < H / 4; ++k4) {                               \
        float4 wv = w4[k4];                                            \
        int k = k4 * 4;                                                \
        _Pragma("unroll") for (int s = 0; s < NS; ++s)                 \
            acc[s] = fmaf(wv.x, SRC[k][s], acc[s]);                    \
        _Pragma("unroll") for (int s = 0; s < NS; ++s)                 \
            acc[s] = fmaf(wv.y, SRC[k + 1][s], acc[s]);                \
        _Pragma("unroll") for (int s = 0; s < NS; ++s)                 \
            acc[s] = fmaf(wv.z, SRC[k + 2][s], acc[s]);                \
        _Pragma("unroll") for (int s = 0; s < NS; ++s)                 \
            acc[s] = fmaf(wv.w, SRC[k + 3][s], acc[s]);                \
    }                                                                  \
}

__global__ __launch_bounds__(256) void mlp_kernel(
    const float* __restrict__ x,
    const float* __restrict__ w_in, const float* __restrict__ b_in,
    const float* __restrict__ w0,   const float* __restrict__ b0,
    const float* __restrict__ w1,   const float* __restrict__ b1,
    const float* __restrict__ w_out,const float* __restrict__ b_out,
    float* __restrict__ w2buf, float* __restrict__ cbuf)
{
    __shared__ float hA[H][NS];
    __shared__ float hB[H][NS];
    const int j = threadIdx.x;
    const int bbase = blockIdx.x * NS;

    if (j < NPARAMS * NS) {
        int k = j / NS, s = j % NS;
        hA[k][s] = x[(bbase + s) * XCOLS + D + k];
    }
    __syncthreads();

    float acc[NS];

    // layer in: 16 -> 256, relu   (hA -> hB)
    {
        float bb = b_in[j];
        #pragma unroll
        for (int s = 0; s < NS; ++s) acc[s] = bb;
        #pragma unroll
        for (int k = 0; k < NPARAMS; ++k) {
            float wv = w_in[j * NPARAMS + k];
            #pragma unroll
            for (int s = 0; s < NS; ++s) acc[s] = fmaf(wv, hA[k][s], acc[s]);
        }
        #pragma unroll
        for (int s = 0; s < NS; ++s) hB[j][s] = fmaxf(acc[s], 0.f);
    }
    __syncthreads();

    LAYER256(w0, b0, hB);
    #pragma unroll
    for (int s = 0; s < NS; ++s) hA[j][s] = fmaxf(acc[s], 0.f);
    __syncthreads();

    LAYER256(w1, b1, hA);
    #pragma unroll
    for (int s = 0; s < NS; ++s) hB[j][s] = fmaxf(acc[s], 0.f);
    __syncthreads();

    LAYER256(w_out, b_out, hB);
    #pragma unroll
    for (int s = 0; s < NS; ++s) {
        float coef = acc[s];
        int b = bbase + s;
        if (j < D) {
            float om = fmaf(coef, 1.5f, 0.5f);          // omega0
            w2buf[b * D + j] = om * om * INV_2PI_F;     // omega0^2 / (2*pi)
        } else {
            cbuf[b * D + (j - D)] = coef;               // coupling (identity affine)
        }
    }
}

// ---------------- ODE: revolution-domain RK4, 2 samples per wave -------------
// phi = theta/(2pi), u = v/(2pi):
//   dphi/dt = u
//   du/dt   = -(w^2/2pi) * sin_hw(phi) + cl*(phiL-phi) + c*(phiR-phi)
// Lane l owns oscillators 2l,2l+1 of TWO samples (independent chains -> ILP).
// Cross-lane neighbor exchange via DPP wave rotates.

__device__ __forceinline__ float rot_from_lower(float v) {  // lane n <- lane (n-1)&63
    return __int_as_float(__builtin_amdgcn_mov_dpp(__float_as_int(v), 0x13C, 0xF, 0xF, false)); // wave_ror:1
}
__device__ __forceinline__ float rot_from_upper(float v) {  // lane n <- lane (n+1)&63
    return __int_as_float(__builtin_amdgcn_mov_dpp(__float_as_int(v), 0x134, 0xF, 0xF, false)); // wave_rol:1
}

__global__ __launch_bounds__(256) void ode_kernel(
    const float* __restrict__ x,
    const float* __restrict__ w2buf,
    const float* __restrict__ cbuf,
    float* __restrict__ out,
    int nstep, float dt)
{
    const int lane = threadIdx.x & 63;
    const int wid  = threadIdx.x >> 6;
    const int bA   = blockIdx.x * 8 + wid * 2;   // two consecutive samples

    float th0[2], th1[2], v0[2], v1[2];
    float nw0[2], nw1[2], c0[2], c1[2], cl[2];

    #pragma unroll
    for (int s = 0; s < 2; ++s) {
        int b  = bA + s;
        int i0 = b * D + 2 * lane;
        float2 xi  = *reinterpret_cast<const float2*>(&x[b * XCOLS + 2 * lane]);
        th0[s] = xi.x - 0.5f;            // phi0 = (x*2pi - pi)/2pi = x - 1/2
        th1[s] = xi.y - 0.5f;
        v0[s] = 0.f; v1[s] = 0.f;
        float2 w2p = *reinterpret_cast<const float2*>(&w2buf[i0]);
        float2 cp  = *reinterpret_cast<const float2*>(&cbuf[i0]);
        nw0[s] = -w2p.x; nw1[s] = -w2p.y;
        c0[s] = cp.x;    c1[s] = cp.y;
        cl[s] = cbuf[(i0 + NTOT - 1) % NTOT];   // flat-roll left coupling of osc 2l
    }

    auto deriv = [&](const float t0[2], const float t1[2], float a0[2], float a1[2]) {
        #pragma unroll
        for (int s = 0; s < 2; ++s) {
            float L0 = rot_from_lower(t1[s]);   // phi of osc 2l-1 (wraps 0 -> 127)
            float R1 = rot_from_upper(t0[s]);   // phi of osc 2l+2 (wraps 63 -> 0)
            float s0 = __builtin_amdgcn_sinf(t0[s]);   // sin(2pi*phi), raw v_sin_f32
            float s1 = __builtin_amdgcn_sinf(t1[s]);
            float dd  = t1[s] - t0[s];
            float cpl = c0[s] * dd;
            a0[s] = fmaf(s0, nw0[s], fmaf(cl[s], L0 - t0[s],  cpl));
            a1[s] = fmaf(s1, nw1[s], fmaf(c1[s], R1 - t1[s], -cpl));
        }
    };

    const float hdt   = 0.5f * dt;
    const float sixth = dt * (1.0f / 6.0f);

    for (int it = 0; it < nstep; ++it) {
        float a1_0[2], a1_1[2];
        deriv(th0, th1, a1_0, a1_1);

        float t2_0[2], t2_1[2], k2_0[2], k2_1[2];
        #pragma unroll
        for (int s = 0; s < 2; ++s) {
            t2_0[s] = fmaf(hdt, v0[s], th0[s]);   t2_1[s] = fmaf(hdt, v1[s], th1[s]);
            k2_0[s] = fmaf(hdt, a1_0[s], v0[s]);  k2_1[s] = fmaf(hdt, a1_1[s], v1[s]);
        }
        float a2_0[2], a2_1[2];
        deriv(t2_0, t2_1, a2_0, a2_1);

        float t3_0[2], t3_1[2], k3_0[2], k3_1[2];
        #pragma unroll
        for (int s = 0; s < 2; ++s) {
            t3_0[s] = fmaf(hdt, k2_0[s], th0[s]); t3_1[s] = fmaf(hdt, k2_1[s], th1[s]);
            k3_0[s] = fmaf(hdt, a2_0[s], v0[s]);  k3_1[s] = fmaf(hdt, a2_1[s], v1[s]);
        }
        float a3_0[2], a3_1[2];
        deriv(t3_0, t3_1, a3_0, a3_1);

        float t4_0[2], t4_1[2], k4_0[2], k4_1[2];
        #pragma unroll
        for (int s = 0; s < 2; ++s) {
            t4_0[s] = fmaf(dt, k3_0[s], th0[s]);  t4_1[s] = fmaf(dt, k3_1[s], th1[s]);
            k4_0[s] = fmaf(dt, a3_0[s], v0[s]);   k4_1[s] = fmaf(dt, a3_1[s], v1[s]);
        }
        float a4_0[2], a4_1[2];
        deriv(t4_0, t4_1, a4_0, a4_1);

        #pragma unroll
        for (int s = 0; s < 2; ++s) {
            th0[s] += sixth * (v0[s] + 2.f * (k2_0[s] + k3_0[s]) + k4_0[s]);
            th1[s] += sixth * (v1[s] + 2.f * (k2_1[s] + k3_1[s]) + k4_1[s]);
            v0[s]  += sixth * (a1_0[s] + 2.f * (a2_0[s] + a3_0[s]) + a4_0[s]);
            v1[s]  += sixth * (a1_1[s] + 2.f * (a2_1[s] + a3_1[s]) + a4_1[s]);
        }
    }

    #pragma unroll
    for (int s = 0; s < 2; ++s) {
        int i0 = (bA + s) * D + 2 * lane;
        float2 o = make_float2(th0[s] * OUT_SCALE, th1[s] * OUT_SCALE);
        *reinterpret_cast<float2*>(&out[i0]) = o;
    }
}

extern "C" void kernel_launch(void* const* d_in, const int* in_sizes, int n_in,
                              void* d_out, int out_size, void* d_ws, size_t ws_size,
                              hipStream_t stream) {
    const float* x     = (const float*)d_in[0];
    const float* w_in  = (const float*)d_in[1];
    const float* b_in  = (const float*)d_in[2];
    const float* w0    = (const float*)d_in[3];
    const float* b0    = (const float*)d_in[4];
    const float* w1    = (const float*)d_in[5];
    const float* b1    = (const float*)d_in[6];
    const float* w_out = (const float*)d_in[7];
    const float* b_out = (const float*)d_in[8];

    float* w2buf = (float*)d_ws;          // omega0^2/(2pi), NTOT floats
    float* cbuf  = w2buf + NTOT;          // coupling, NTOT floats
    float* out   = (float*)d_out;

    mlp_kernel<<<BATCH / NS, 256, 0, stream>>>(x, w_in, b_in, w0, b0, w1, b1,
                                               w_out, b_out, w2buf, cbuf);

    const int nstep = 64;
    const float dtf = (float)((59.0 / 30.0) / nstep);
    ode_kernel<<<BATCH / 8, 256, 0, stream>>>(x, w2buf, cbuf, out, nstep, dtf);
}